// Round 15
// baseline (716.580 us; speedup 1.0000x reference)
//
#include <hip/hip_runtime.h>
#include <math.h>

#define Tn 64
#define Bn 32
#define Pn 9
#define Dn 512
#define TBn 2048
#define G3 1536
#define NCH 16

using short8 = __attribute__((ext_vector_type(8))) short;
using f32x4  = __attribute__((ext_vector_type(4))) float;
typedef unsigned long long ull;
typedef unsigned int uint;

__device__ __forceinline__ float fsigmoid(float x){ return 1.0f/(1.0f+__expf(-x)); }
__device__ __forceinline__ ushort f2bf(float x){
  unsigned u = __float_as_uint(x);
  return (ushort)((u + 0x7FFFu + ((u>>16)&1u)) >> 16);
}
__device__ __forceinline__ float bf2f(ushort h){
  return __uint_as_float(((unsigned)h)<<16);
}
__device__ __forceinline__ uint pk32(float x){
  ushort h = f2bf(x);
  ushort l = f2bf(x - bf2f(h));
  return ((uint)h << 16) | (uint)l;
}
// async global->LDS, 16B per lane; LDS dest = wave-uniform base + lane*16
__device__ __forceinline__ void gload_lds16(const ushort* g, ushort* l){
  __builtin_amdgcn_global_load_lds(
      (const __attribute__((address_space(1))) void*)g,
      (__attribute__((address_space(3))) void*)l, 16, 0, 0);
}

// device-coherent (agent) relaxed accessors: bypass non-coherent L1/L2.
__device__ __forceinline__ ull ld_agent8(const ull* p){
  return __hip_atomic_load(p, __ATOMIC_RELAXED, __HIP_MEMORY_SCOPE_AGENT);
}
__device__ __forceinline__ void st_agent8(ull* p, ull v){
  __hip_atomic_store(p, v, __ATOMIC_RELAXED, __HIP_MEMORY_SCOPE_AGENT);
}
__device__ __forceinline__ unsigned ld_agent4(const int* p){
  return (unsigned)__hip_atomic_load(p, __ATOMIC_RELAXED, __HIP_MEMORY_SCOPE_AGENT);
}
__device__ __forceinline__ void st_agent4(int* p, int v){
  __hip_atomic_store(p, v, __ATOMIC_RELAXED, __HIP_MEMORY_SCOPE_AGENT);
}
__device__ __forceinline__ float ulo(ull v){ return __uint_as_float((unsigned)v); }
__device__ __forceinline__ float uhi(ull v){ return __uint_as_float((unsigned)(v>>32)); }
__device__ __forceinline__ ull upack(float a, float b){
  return ((ull)__float_as_uint(b) << 32) | (ull)__float_as_uint(a);
}

// ---------- prep ----------
__global__ void k_prep(const float* __restrict__ qmask, int* __restrict__ qi,
                       int* __restrict__ qni, float* __restrict__ h0A,
                       float* __restrict__ h0B, float* __restrict__ out,
                       int* __restrict__ counts, int* __restrict__ lists,
                       int* __restrict__ dcnt, int* __restrict__ dlist,
                       int* __restrict__ rowflag, int* __restrict__ zrow){
  int t = blockIdx.x; int tid = threadIdx.x;
  int gidx = blockIdx.x*256 + tid;
  if (gidx < 16) counts[gidx] = 0;
  if (gidx < 32) zrow[gidx] = 0;          // 128B zero page for gather padding
  if (gidx < Bn*Pn*NCH) st_agent4(&rowflag[gidx], 0);
  for (int i=gidx; i<9*4096; i+=64*256) lists[i] = -1;
  __shared__ int qis[32], qnis[32];
  __shared__ int cnt9[9];
  if (tid < 9) cnt9[tid] = 0;
  if (tid < Bn){
    int b = tid;
    const float* qm = qmask + ((size_t)t*Bn + b)*Pn;
    int best = 0; float bv = qm[0];
    #pragma unroll
    for (int p=1;p<Pn;p++){ float v=qm[p]; if (v>bv){bv=v;best=p;} }
    qi[t*Bn+b] = best; qis[b] = best;
    int tn = (t==Tn-1)? t : t+1;
    const float* qmn = qmask + ((size_t)tn*Bn + b)*Pn;
    best = 0; bv = qmn[0];
    #pragma unroll
    for (int p=1;p<Pn;p++){ float v=qmn[p]; if (v>bv){bv=v;best=p;} }
    qni[t*Bn+b] = best; qnis[b] = best;
  }
  __syncthreads();
  if (tid < Bn){
    int sp = qis[tid], lp = qnis[tid];
    if (sp == lp){
      int i = atomicAdd(&cnt9[sp], 1);
      dlist[(t*9+sp)*32 + i] = tid | 256 | 512;
    } else {
      int i = atomicAdd(&cnt9[sp], 1);
      dlist[(t*9+sp)*32 + i] = tid | 256;
      int j = atomicAdd(&cnt9[lp], 1);
      dlist[(t*9+lp)*32 + j] = tid | 512;
    }
  }
  __syncthreads();
  if (tid < 9) dcnt[t*9+tid] = cnt9[tid];
  for (int i=tid; i<2304; i+=256){ h0A[t*2304 + i] = 0.f; h0B[t*2304 + i] = 0.f; }
  for (int i=tid; i<256;  i+=256) out[t*256 + i] = 0.f;
}

// ---------- aux: gi gather lists + version pack into dlist ----------
__global__ void k_aux(const int* __restrict__ qi, const int* __restrict__ qni,
                      int* __restrict__ counts, int* __restrict__ lists,
                      const int* __restrict__ dcnt, int* __restrict__ dlist){
  int tid = threadIdx.x;
  if (blockIdx.x < 16){
    int id = blockIdx.x*256 + tid;
    int role = id >> 11, tb = id & (TBn-1);
    int p = role ? qni[tb] : qi[tb];
    int slot = atomicAdd(&counts[p], 1);
    lists[p*4096 + slot] = id;
  } else {
    for (int idx = tid; idx < Bn*Pn; idx += 256){
      int b = idx / Pn, pp = idx % Pn;
      int v = 0;
      for (int t=0;t<Tn;t++){
        if (qi[t*Bn+b]==pp || qni[t*Bn+b]==pp){
          int nn = dcnt[t*9+pp];
          int base = (t*9+pp)*32;
          for (int i=0;i<nn;i++){
            if ((dlist[base+i] & 31) == b){ dlist[base+i] |= (v<<16); break; }
          }
          v++;
        }
      }
    }
  }
}

// ---------- batched f32 -> [hi|lo] bf16 pack ----------
struct PkD { const float* s; ushort* d; int n; };
__global__ __launch_bounds__(256) void k_packB(PkD p0, PkD p1, PkD p2, PkD p3,
                                               PkD p4, PkD p5, PkD p6, PkD p7){
  PkD D;
  switch (blockIdx.z){
    case 0: D=p0; break; case 1: D=p1; break; case 2: D=p2; break; case 3: D=p3; break;
    case 4: D=p4; break; case 5: D=p5; break; case 6: D=p6; break; default: D=p7; break;
  }
  int total = D.n * 128;
  for (int idx = blockIdx.x*256 + threadIdx.x; idx < total; idx += gridDim.x*256){
    int r = idx >> 7, c4 = idx & 127;
    float4 v = ((const float4*)D.s)[idx];
    ushort h0=f2bf(v.x), h1=f2bf(v.y), h2=f2bf(v.z), h3=f2bf(v.w);
    ushort l0=f2bf(v.x-bf2f(h0)), l1=f2bf(v.y-bf2f(h1)),
           l2=f2bf(v.z-bf2f(h2)), l3=f2bf(v.w-bf2f(h3));
    ushort* base = D.d + (size_t)r*1024;
    *(ushort4*)(base + c4*4)       = make_ushort4(h0,h1,h2,h3);
    *(ushort4*)(base + 512 + c4*4) = make_ushort4(l0,l1,l2,l3);
  }
}

// ---------- batched MFMA GEMM, 64x64 tile, single-pass K, global_load_lds staging ----------
struct MMd {
  const ushort* A; const ushort* B; float* C; const float* bias; ushort* Cpk;
  int asr, ahi, alo, bsr, bhi, blo, ldc, gx;
};
__global__ __launch_bounds__(256) void k_mmB(MMd d0, MMd d1, MMd d2, MMd d3){
  MMd d;
  switch (blockIdx.z){
    case 0: d=d0; break; case 1: d=d1; break; case 2: d=d2; break; default: d=d3; break;
  }
  if ((int)blockIdx.x >= d.gx) return;
  __shared__ ushort AshH[64*64];
  __shared__ ushort AshL[64*64];
  __shared__ ushort BshH[64*64];
  __shared__ ushort BshL[64*64];
  int bm = blockIdx.y*64, bn = blockIdx.x*64;
  int tid = threadIdx.x;
  int lane = tid & 63, w = tid >> 6;
  int wm = (w>>1)*32, wn = (w&1)*32;
  f32x4 acc[2][2] = {};
  const ushort* Ah = d.A + d.ahi;
  const ushort* Al = d.A + d.alo;
  const ushort* Bh = d.B + d.bhi;
  const ushort* Bl = d.B + d.blo;
  // pre-swizzled source addressing (involution): lane writes LDS linearly at base+16*lane
  int lrow = lane >> 3;                     // 0..7
  int lg   = (lane & 7) ^ (lrow & 7);       // swizzled col group
  int ro0  = 8*w + lrow;                    // rows 0..31 set
  int ro1  = 32 + 8*w + lrow;               // rows 32..63 set
  int lb0  = 512*w;                         // LDS ushort base, set 0
  int lb1  = 2048 + 512*w;                  // LDS ushort base, set 1
  for (int k0=0; k0<512; k0+=64){
    __syncthreads();
    gload_lds16(Ah + (size_t)(bm+ro0)*d.asr + k0 + lg*8, AshH + lb0);
    gload_lds16(Ah + (size_t)(bm+ro1)*d.asr + k0 + lg*8, AshH + lb1);
    gload_lds16(Al + (size_t)(bm+ro0)*d.asr + k0 + lg*8, AshL + lb0);
    gload_lds16(Al + (size_t)(bm+ro1)*d.asr + k0 + lg*8, AshL + lb1);
    gload_lds16(Bh + (size_t)(bn+ro0)*d.bsr + k0 + lg*8, BshH + lb0);
    gload_lds16(Bh + (size_t)(bn+ro1)*d.bsr + k0 + lg*8, BshH + lb1);
    gload_lds16(Bl + (size_t)(bn+ro0)*d.bsr + k0 + lg*8, BshL + lb0);
    gload_lds16(Bl + (size_t)(bn+ro1)*d.bsr + k0 + lg*8, BshL + lb1);
    __syncthreads();
    #pragma unroll
    for (int kk=0; kk<2; ++kk){
      int gs = kk*4 + (lane>>4);
      short8 afh[2], afl[2], bfh[2], bfl[2];
      #pragma unroll
      for (int mi=0; mi<2; ++mi){
        int row = wm + mi*16 + (lane&15);
        afh[mi] = *(const short8*)(AshH + row*64 + ((gs ^ (row&7))*8));
        afl[mi] = *(const short8*)(AshL + row*64 + ((gs ^ (row&7))*8));
      }
      #pragma unroll
      for (int ni=0; ni<2; ++ni){
        int row = wn + ni*16 + (lane&15);
        bfh[ni] = *(const short8*)(BshH + row*64 + ((gs ^ (row&7))*8));
        bfl[ni] = *(const short8*)(BshL + row*64 + ((gs ^ (row&7))*8));
      }
      #pragma unroll
      for (int mi=0; mi<2; ++mi)
        #pragma unroll
        for (int ni=0; ni<2; ++ni){
          acc[mi][ni] = __builtin_amdgcn_mfma_f32_16x16x32_bf16(afh[mi], bfh[ni], acc[mi][ni], 0,0,0);
          acc[mi][ni] = __builtin_amdgcn_mfma_f32_16x16x32_bf16(afh[mi], bfl[ni], acc[mi][ni], 0,0,0);
          acc[mi][ni] = __builtin_amdgcn_mfma_f32_16x16x32_bf16(afl[mi], bfh[ni], acc[mi][ni], 0,0,0);
        }
    }
  }
  #pragma unroll
  for (int mi=0; mi<2; ++mi){
    #pragma unroll
    for (int ni=0; ni<2; ++ni){
      #pragma unroll
      for (int i=0;i<4;i++){
        int row = bm + wm + mi*16 + (lane>>4)*4 + i;
        int col = bn + wn + ni*16 + (lane&15);
        float v = acc[mi][ni][i];
        if (d.bias) v += d.bias[col];
        if (d.C) d.C[(size_t)row*d.ldc + col] = v;
        if (d.Cpk){
          ushort h = f2bf(v);
          d.Cpk[(size_t)row*2*d.ldc + col] = h;
          d.Cpk[(size_t)row*2*d.ldc + d.ldc + col] = f2bf(v - bf2f(h));
        }
      }
    }
  }
}

// ---------- gather MFMA GEMM, 64x64 tile, single-pass K, global_load_lds staging ----------
__global__ __launch_bounds__(256) void k_mm_g(
    const ushort* __restrict__ Spk0, const ushort* __restrict__ Spk1,
    const ushort* __restrict__ Wihpk, const float* __restrict__ bih,
    const int* __restrict__ counts, const int* __restrict__ lists,
    float* __restrict__ gis, float* __restrict__ gil,
    const ushort* __restrict__ zrow)
{
  int p = blockIdx.z;
  int mt = blockIdx.y;
  if (mt*64 >= counts[p]) return;
  int bn = blockIdx.x*64;
  __shared__ ushort AshH[64*64];
  __shared__ ushort AshL[64*64];
  __shared__ ushort BshH[64*64];
  __shared__ ushort BshL[64*64];
  __shared__ int rid[64];
  int tid = threadIdx.x;
  int lane = tid & 63, w = tid >> 6;
  int wm = (w>>1)*32, wn = (w&1)*32;
  if (tid < 64) rid[tid] = lists[p*4096 + mt*64 + tid];
  __syncthreads();
  f32x4 acc[2][2] = {};
  int lrow = lane >> 3;
  int lg   = (lane & 7) ^ (lrow & 7);
  int ro0  = 8*w + lrow;
  int ro1  = 32 + 8*w + lrow;
  int lb0  = 512*w;
  int lb1  = 2048 + 512*w;
  int idA0 = rid[ro0], idA1 = rid[ro1];
  const ushort* rowp0 = (idA0 >= 0) ? (((idA0>>11)? Spk1:Spk0) + (size_t)(idA0 & (TBn-1))*1024) : nullptr;
  const ushort* rowp1 = (idA1 >= 0) ? (((idA1>>11)? Spk1:Spk0) + (size_t)(idA1 & (TBn-1))*1024) : nullptr;
  const ushort* Wb = Wihpk + (size_t)(p*G3 + bn)*1024;
  const ushort* zr = zrow + lg*8;
  for (int k0=0; k0<512; k0+=64){
    __syncthreads();
    gload_lds16(rowp0 ? rowp0 + k0 + lg*8       : zr, AshH + lb0);
    gload_lds16(rowp1 ? rowp1 + k0 + lg*8       : zr, AshH + lb1);
    gload_lds16(rowp0 ? rowp0 + 512 + k0 + lg*8 : zr, AshL + lb0);
    gload_lds16(rowp1 ? rowp1 + 512 + k0 + lg*8 : zr, AshL + lb1);
    gload_lds16(Wb + (size_t)ro0*1024 + k0 + lg*8,       BshH + lb0);
    gload_lds16(Wb + (size_t)ro1*1024 + k0 + lg*8,       BshH + lb1);
    gload_lds16(Wb + (size_t)ro0*1024 + 512 + k0 + lg*8, BshL + lb0);
    gload_lds16(Wb + (size_t)ro1*1024 + 512 + k0 + lg*8, BshL + lb1);
    __syncthreads();
    #pragma unroll
    for (int kk=0; kk<2; ++kk){
      int gs = kk*4 + (lane>>4);
      short8 afh[2], afl[2], bfh[2], bfl[2];
      #pragma unroll
      for (int mi=0; mi<2; ++mi){
        int row = wm + mi*16 + (lane&15);
        afh[mi] = *(const short8*)(AshH + row*64 + ((gs ^ (row&7))*8));
        afl[mi] = *(const short8*)(AshL + row*64 + ((gs ^ (row&7))*8));
      }
      #pragma unroll
      for (int ni=0; ni<2; ++ni){
        int row = wn + ni*16 + (lane&15);
        bfh[ni] = *(const short8*)(BshH + row*64 + ((gs ^ (row&7))*8));
        bfl[ni] = *(const short8*)(BshL + row*64 + ((gs ^ (row&7))*8));
      }
      #pragma unroll
      for (int mi=0; mi<2; ++mi)
        #pragma unroll
        for (int ni=0; ni<2; ++ni){
          acc[mi][ni] = __builtin_amdgcn_mfma_f32_16x16x32_bf16(afh[mi], bfh[ni], acc[mi][ni], 0,0,0);
          acc[mi][ni] = __builtin_amdgcn_mfma_f32_16x16x32_bf16(afh[mi], bfl[ni], acc[mi][ni], 0,0,0);
          acc[mi][ni] = __builtin_amdgcn_mfma_f32_16x16x32_bf16(afl[mi], bfh[ni], acc[mi][ni], 0,0,0);
        }
    }
  }
  #pragma unroll
  for (int mi=0; mi<2; ++mi){
    #pragma unroll
    for (int ni=0; ni<2; ++ni){
      #pragma unroll
      for (int i=0;i<4;i++){
        int lrow2 = wm + mi*16 + (lane>>4)*4 + i;
        int id = rid[lrow2];
        if (id < 0) continue;
        int col = bn + wn + ni*16 + (lane&15);
        float v = acc[mi][ni][i] + bih[p*G3 + col];
        float* dst = ((id>>11) ? gil : gis) + (size_t)(id & (TBn-1))*G3;
        dst[col] = v;
      }
    }
  }
}

// ---------- batched per-t batch-axis softmax + context scale ----------
__global__ __launch_bounds__(256) void k_scoreB(
      const float* __restrict__ qx0, const ushort* __restrict__ kh0,
      const ushort* __restrict__ kl0, const float* __restrict__ px0,
      const float* __restrict__ bp0, ushort* __restrict__ sp0,
      const float* __restrict__ qx1, const ushort* __restrict__ kh1,
      const ushort* __restrict__ kl1, const float* __restrict__ px1,
      const float* __restrict__ bp1, ushort* __restrict__ sp1, int ksr){
  const float* qx; const ushort* khi; const ushort* klo;
  const float* pkx; const float* bp; ushort* spk;
  if (blockIdx.y == 0){ qx=qx0; khi=kh0; klo=kl0; pkx=px0; bp=bp0; spk=sp0; }
  else                { qx=qx1; khi=kh1; klo=kl1; pkx=px1; bp=bp1; spk=sp1; }
  int t = blockIdx.x; int tid = threadIdx.x;
  __shared__ float part[256];
  __shared__ float dots[32];
  __shared__ float sc[32];
  int b = tid >> 3, j = tid & 7;
  const float* q = qx + ((size_t)t*Bn + b)*Dn;
  const ushort* kh = khi + ((size_t)t*Bn + b)*ksr;
  const ushort* kl = klo + ((size_t)t*Bn + b)*ksr;
  float s = 0.f;
  for (int d=j; d<Dn; d+=8) s = fmaf(q[d], bf2f(kh[d]) + bf2f(kl[d]), s);
  part[tid] = s;
  __syncthreads();
  if (tid < 32){
    float acc = 0.f;
    #pragma unroll
    for (int jj=0;jj<8;jj++) acc += part[tid*8+jj];
    dots[tid] = acc;
  }
  __syncthreads();
  if (tid < 32){
    float mx = dots[0];
    for (int o=1;o<32;o++) mx = fmaxf(mx, dots[o]);
    sc[tid] = __expf(dots[tid] - mx);
  }
  __syncthreads();
  float myscore = 0.f;
  if (tid < 32){
    float sum = 0.f;
    for (int o=0;o<32;o++) sum += sc[o];
    myscore = sc[tid] / sum;
  }
  __syncthreads();
  if (tid < 32) sc[tid] = myscore;
  __syncthreads();
  for (int idx=tid; idx<Bn*Dn; idx+=256){
    int bb = idx >> 9, d = idx & (Dn-1);
    float v = fmaf(sc[bb], pkx[((size_t)t*Bn+bb)*Dn + d], bp[d]);
    ushort h = f2bf(v);
    size_t o = ((size_t)t*Bn+bb)*1024 + d;
    spk[o] = h;
    spk[o + 512] = f2bf(v - bf2f(h));
  }
}

// ---------- persistent recurrence: per-row version flags + MFMA matvec (R13) ----------
#define DC 32
#define NT 6
__global__ __launch_bounds__(512, 1) void k_rec(
    float* hA, float* hB,
    const int* __restrict__ dcnt, const int* __restrict__ dlist,
    const float* __restrict__ Whh, const float* __restrict__ bhh,
    const float* __restrict__ gis, const float* __restrict__ gil,
    float* __restrict__ out, int* rowflag){
  int p  = blockIdx.x;
  int ci = blockIdx.y;
  int d0 = ci * DC;
  int tid = threadIdx.x;
  int wave = tid >> 6, lane = tid & 63;

  __shared__ float4 hsh4[16][130];   // staged h rows (f32, XOR-swizzled) for ew
  __shared__ uint   ab16[16][516];   // staged h rows as packed bf16 hi|lo for MFMA
  __shared__ float  ghs[16][97];     // gh per entry, lr = gate*32 + dd
  __shared__ int    dls[32];

  short8 Bh[16], Bl[16];
  if (wave < NT){
    int wrow = wave*16 + (lane & 15);
    int grow = (wrow >> 5)*Dn + d0 + (wrow & 31);
    const float* wsrc = Whh + ((size_t)p*G3 + grow)*Dn + (lane>>4)*8;
    #pragma unroll
    for (int ks=0; ks<16; ++ks){
      float4 w0 = *(const float4*)(wsrc + ks*32);
      float4 w1 = *(const float4*)(wsrc + ks*32 + 4);
      float xs[8] = {w0.x,w0.y,w0.z,w0.w,w1.x,w1.y,w1.z,w1.w};
      #pragma unroll
      for (int j=0;j<8;j++){
        ushort hh = f2bf(xs[j]);
        Bh[ks][j] = (short)hh;
        Bl[ks][j] = (short)f2bf(xs[j] - bf2f(hh));
      }
    }
  }
  int dd0 = (tid & 15)*2, dfix = d0 + dd0;
  float bhr0 = bhh[p*G3 + dfix],        bhr1 = bhh[p*G3 + dfix + 1];
  float bhz0 = bhh[p*G3 + Dn + dfix],   bhz1 = bhh[p*G3 + Dn + dfix + 1];
  float bhn0 = bhh[p*G3 + 2*Dn + dfix], bhn1 = bhh[p*G3 + 2*Dn + dfix + 1];

  int entC = 0;
  if (tid < 32) entC = dlist[(0*9 + p)*32 + tid];

  for (int t=0; t<Tn; ++t){
    __syncthreads();
    if (tid < 32) dls[tid] = entC;
    __syncthreads();
    if (t+1 < Tn && tid < 32) entC = dlist[((t+1)*9 + p)*32 + tid];
    int n = dcnt[t*9+p];
    if (!n) continue;

    float pg[12];
    {
      int i = tid >> 4;
      if (i < n && i < 16){
        int ent = dls[i]; int b = ent & 31;
        if (ent & 256){
          const float* gS = gis + (size_t)(t*Bn + b)*G3;
          pg[0]=gS[dfix]; pg[1]=gS[dfix+1]; pg[2]=gS[Dn+dfix]; pg[3]=gS[Dn+dfix+1];
          pg[4]=gS[2*Dn+dfix]; pg[5]=gS[2*Dn+dfix+1];
        }
        if (ent & 512){
          const float* gL = gil + (size_t)(t*Bn + b)*G3;
          pg[6]=gL[dfix]; pg[7]=gL[dfix+1]; pg[8]=gL[Dn+dfix]; pg[9]=gL[Dn+dfix+1];
          pg[10]=gL[2*Dn+dfix]; pg[11]=gL[2*Dn+dfix+1];
        }
      }
    }

    {
      int i0 = wave*4 + (lane >> 4);
      if (i0 < n){
        int ent = dls[i0];
        unsigned need = (unsigned)(ent >> 16);
        if (need){
          int b = ent & 31;
          const int* cell = &rowflag[(b*Pn + p)*NCH + (lane & 15)];
          while (ld_agent4(cell) < need) __builtin_amdgcn_s_sleep(1);
        }
      }
    }
    __syncthreads();

    for (int g0=0; g0<n; g0+=16){
      int gn = n - g0; if (gn > 16) gn = 16;
      for (int idx=tid; idx<gn*128; idx+=512){
        int r = idx >> 7, q = idx & 127;
        int ent = dls[g0+r];
        int b = ent & 31;
        const float* hsrc = ((ent>>16) & 1) ? hB : hA;
        const ull* src = (const ull*)(hsrc + ((size_t)b*Pn + p)*Dn) + q*2;
        ull v0 = ld_agent8(src), v1 = ld_agent8(src+1);
        float4 f; f.x = ulo(v0); f.y = uhi(v0); f.z = ulo(v1); f.w = uhi(v1);
        hsh4[r][q ^ ((q>>3)&7)] = f;
        uint4 pk; pk.x = pk32(f.x); pk.y = pk32(f.y); pk.z = pk32(f.z); pk.w = pk32(f.w);
        *(uint4*)&ab16[r][q*4] = pk;
      }
      __syncthreads();

      if (wave < NT){
        f32x4 acc = {0.f,0.f,0.f,0.f};
        int arow = lane & 15;
        int kq   = (lane >> 4)*8;
        #pragma unroll
        for (int ks=0; ks<16; ++ks){
          uint4 u0 = *(const uint4*)&ab16[arow][ks*32 + kq];
          uint4 u1 = *(const uint4*)&ab16[arow][ks*32 + kq + 4];
          uint uu[8] = {u0.x,u0.y,u0.z,u0.w,u1.x,u1.y,u1.z,u1.w};
          short8 Ah, Al;
          #pragma unroll
          for (int j=0;j<8;j++){
            Ah[j] = (short)(uu[j] >> 16);
            Al[j] = (short)(uu[j] & 0xffffu);
          }
          acc = __builtin_amdgcn_mfma_f32_16x16x32_bf16(Ah, Bh[ks], acc, 0,0,0);
          acc = __builtin_amdgcn_mfma_f32_16x16x32_bf16(Ah, Bl[ks], acc, 0,0,0);
          acc = __builtin_amdgcn_mfma_f32_16x16x32_bf16(Al, Bh[ks], acc, 0,0,0);
        }
        #pragma unroll
        for (int i=0;i<4;i++)
          ghs[(lane>>4)*4 + i][wave*16 + (lane & 15)] = acc[i];
      }
      __syncthreads();

      if (tid < gn*16){
        int i = tid >> 4;
        int ent = dls[g0+i];
        int b = ent & 31;
        bool S = (ent & 256) != 0, L = (ent & 512) != 0;
        int v = ent >> 16;
        float* hdst = (v & 1) ? hA : hB;
        int qq = dfix >> 2;
        float4 u = hsh4[i][qq ^ ((qq>>3)&7)];
        float hv0 = (dfix & 2) ? u.z : u.x;
        float hv1 = (dfix & 2) ? u.w : u.y;
        float ghr0 = ghs[i][dd0]    + bhr0, ghr1 = ghs[i][dd0+1]    + bhr1;
        float ghz0 = ghs[i][32+dd0] + bhz0, ghz1 = ghs[i][32+dd0+1] + bhz1;
        float ghn0 = ghs[i][64+dd0] + bhn0, ghn1 = ghs[i][64+dd0+1] + bhn1;
        float v0 = hv0, v1 = hv1;
        if (S){
          float i0,i1,i2,i3,i4,i5;
          if (g0 == 0){ i0=pg[0]; i1=pg[1]; i2=pg[2]; i3=pg[3]; i4=pg[4]; i5=pg[5]; }
          else {
            const float* gS = gis + (size_t)(t*Bn + b)*G3;
            i0=gS[dfix]; i1=gS[dfix+1]; i2=gS[Dn+dfix]; i3=gS[Dn+dfix+1];
            i4=gS[2*Dn+dfix]; i5=gS[2*Dn+dfix+1];
          }
          float rg0 = fsigmoid(i0 + ghr0), rg1 = fsigmoid(i1 + ghr1);
          float zg0 = fsigmoid(i2 + ghz0), zg1 = fsigmoid(i3 + ghz1);
          float ng0 = tanhf(fmaf(rg0, ghn0, i4));
          float ng1 = tanhf(fmaf(rg1, ghn1, i5));
          v0 = fmaf(zg0, hv0 - ng0, ng0);
          v1 = fmaf(zg1, hv1 - ng1, ng1);
        }
        if (L){
          float i0,i1,i2,i3,i4,i5;
          if (g0 == 0){ i0=pg[6]; i1=pg[7]; i2=pg[8]; i3=pg[9]; i4=pg[10]; i5=pg[11]; }
          else {
            const float* gL = gil + (size_t)(t*Bn + b)*G3;
            i0=gL[dfix]; i1=gL[dfix+1]; i2=gL[Dn+dfix]; i3=gL[Dn+dfix+1];
            i4=gL[2*Dn+dfix]; i5=gL[2*Dn+dfix+1];
          }
          float rg0 = fsigmoid(i0 + ghr0), rg1 = fsigmoid(i1 + ghr1);
          float zg0 = fsigmoid(i2 + ghz0), zg1 = fsigmoid(i3 + ghz1);
          float ng0 = tanhf(fmaf(rg0, ghn0, i4));
          float ng1 = tanhf(fmaf(rg1, ghn1, i5));
          float hl0 = fmaf(zg0, hv0 - ng0, ng0);
          float hl1 = fmaf(zg1, hv1 - ng1, ng1);
          if (S){ v0 += hl0 - hv0; v1 += hl1 - hv1; }
          else  { v0 = hl0; v1 = hl1; }
        }
        st_agent8((ull*)(hdst + ((size_t)b*Pn + p)*Dn + dfix), upack(v0, v1));
        if (S) *(ull*)(out + ((size_t)(t+1)*Bn + b)*Dn + dfix) = upack(v0, v1);
      }
      __syncthreads();
    }

    if (tid < n){
      int ent = dls[tid];
      st_agent4(&rowflag[((ent & 31)*Pn + p)*NCH + ci], (ent >> 16) + 1);
    }
  }
}

extern "C" void kernel_launch(void* const* d_in, const int* in_sizes, int n_in,
                              void* d_out, int out_size, void* d_ws, size_t ws_size,
                              hipStream_t stream){
  const float* U    = (const float*)d_in[0];
  const float* SK   = (const float*)d_in[1];
  const float* NU   = (const float*)d_in[2];
  const float* LK   = (const float*)d_in[3];
  const float* qmask= (const float*)d_in[5];
  const float* bk   = (const float*)d_in[7];
  const float* bq   = (const float*)d_in[9];
  const float* bp   = (const float*)d_in[11];
  const float* Wk   = (const float*)d_in[6];
  const float* Wq   = (const float*)d_in[8];
  const float* Wp   = (const float*)d_in[10];
  const float* Wih  = (const float*)d_in[12];
  const float* Whh  = (const float*)d_in[13];
  const float* bih  = (const float*)d_in[14];
  const float* bhh  = (const float*)d_in[15];
  float* out = (float*)d_out;

  char* w = (char*)d_ws;
  size_t off = 0;
  auto alloc = [&](size_t bytes)->void*{ void* p = w + off; off += (bytes + 255) & ~(size_t)255; return p; };
  ushort* SKpk = (ushort*)alloc(2048UL*1024*2);
  ushort* LKpk = (ushort*)alloc(2048UL*1024*2);
  ushort* Upk  = (ushort*)alloc(2048UL*1024*2);
  ushort* NUpk = (ushort*)alloc(2048UL*1024*2);
  ushort* Wkpk = (ushort*)alloc(2048UL*1024*2);
  ushort* Wqpk = (ushort*)alloc(2048UL*1024*2);
  ushort* Wppk = (ushort*)alloc(2048UL*1024*2);
  ushort* Wihpk= (ushort*)alloc(13824UL*1024*2);
  ushort* kxApk= (ushort*)alloc(2048UL*2048*2);
  ushort* kxBpk= (ushort*)alloc(2048UL*2048*2);
  float* qxA   = (float*)alloc(2048UL*512*4);
  float* qxB   = (float*)alloc(2048UL*512*4);
  ushort* s0pk = (ushort*)alloc(2048UL*1024*2);
  ushort* s1pk = (ushort*)alloc(2048UL*1024*2);
  float* gis   = (float*)alloc(2048UL*1536*4);
  float* gil   = (float*)alloc(2048UL*1536*4);
  float* hA    = (float*)alloc(32UL*9*512*4);
  float* hB    = (float*)alloc(32UL*9*512*4);
  int* qi      = (int*)alloc(2048*4);
  int* qni     = (int*)alloc(2048*4);
  int* counts  = (int*)alloc(16*4);
  int* lists   = (int*)alloc(9*4096*4);
  int* dcnt    = (int*)alloc(64*9*4);
  int* dlist   = (int*)alloc(64*9*32*4);
  int* rowflag = (int*)alloc(32*9*NCH*4);
  int* zrow    = (int*)alloc(128);
  float* pkx0 = (float*)(void*)SKpk;
  float* pkx1 = (float*)(void*)LKpk;
  float* pkx2 = (float*)(void*)Upk;
  float* pkx3 = (float*)(void*)NUpk;
  (void)ws_size; (void)in_sizes; (void)n_in; (void)out_size;

  dim3 blk(256);

  k_prep<<<64, blk, 0, stream>>>(qmask, qi, qni, hA, hB, out, counts, lists, dcnt, dlist, rowflag, zrow);
  k_aux <<<17, blk, 0, stream>>>(qi, qni, counts, lists, dcnt, dlist);

  {
    PkD p0{SK, SKpk, 2048}, p1{LK, LKpk, 2048}, p2{U, Upk, 2048}, p3{NU, NUpk, 2048};
    PkD p4{Wk, Wkpk, 2048}, p5{Wq, Wqpk, 2048}, p6{Wp, Wppk, 2048}, p7{Wih, Wihpk, 13824};
    k_packB<<<dim3(256,1,8), blk, 0, stream>>>(p0,p1,p2,p3,p4,p5,p6,p7);
  }

  {
    MMd d0{SKpk, Wkpk,                       nullptr, bk,      kxApk, 1024,0,512, 1024,0,512, 1024, 16};
    MMd d1{LKpk, Wkpk+(size_t)1024*1024,     nullptr, bk+1024, kxBpk, 1024,0,512, 1024,0,512, 1024, 16};
    MMd d2{Upk,  Wqpk,                       qxA,     bq,      nullptr,1024,0,512, 1024,0,512, 512,  8};
    MMd d3{NUpk, Wqpk+(size_t)1024*1024,     qxB,     bq+1024, nullptr,1024,0,512, 1024,0,512, 512,  8};
    k_mmB<<<dim3(16,32,4), blk, 0, stream>>>(d0,d1,d2,d3);
  }
  {
    MMd d0{kxApk, Wppk,                      pkx0, nullptr, nullptr, 2048,0,  1024, 1024,0,512, 512, 8};
    MMd d1{kxApk, Wppk+(size_t)512*1024,     pkx1, nullptr, nullptr, 2048,512,1536, 1024,0,512, 512, 8};
    MMd d2{kxBpk, Wppk+(size_t)1024*1024,    pkx2, nullptr, nullptr, 2048,0,  1024, 1024,0,512, 512, 8};
    MMd d3{kxBpk, Wppk+(size_t)1536*1024,    pkx3, nullptr, nullptr, 2048,512,1536, 1024,0,512, 512, 8};
    k_mmB<<<dim3(8,32,4), blk, 0, stream>>>(d0,d1,d2,d3);
  }

  k_scoreB<<<dim3(64,2), blk, 0, stream>>>(qxA, kxApk+0, kxApk+1024, pkx0, bp,      s0pk,
                                           qxB, kxBpk+0, kxBpk+1024, pkx2, bp+1024, s1pk, 2048);

  {
    MMd d0{s0pk, Wqpk+(size_t)512*1024,  qxA, bq+512,  nullptr, 1024,0,512, 1024,0,512, 512, 8};
    MMd d1{s1pk, Wqpk+(size_t)1536*1024, qxB, bq+1536, nullptr, 1024,0,512, 1024,0,512, 512, 8};
    k_mmB<<<dim3(8,32,2), blk, 0, stream>>>(d0,d1,d0,d0);
  }

  k_scoreB<<<dim3(64,2), blk, 0, stream>>>(qxA, kxApk+512, kxApk+1536, pkx1, bp+512,  s0pk,
                                           qxB, kxBpk+512, kxBpk+1536, pkx3, bp+1536, s1pk, 2048);

  k_mm_g<<<dim3(24,64,9), blk, 0, stream>>>(s0pk, s1pk, Wihpk, bih, counts, lists, gis, gil, (const ushort*)zrow);

  k_rec<<<dim3(9,NCH), dim3(512), 0, stream>>>(hA, hB, dcnt, dlist, Whh, bhh, gis, gil, out, rowflag);
}

// Round 16
// 653.878 us; speedup vs baseline: 1.0959x; 1.0959x over previous
//
#include <hip/hip_runtime.h>
#include <math.h>

#define Tn 64
#define Bn 32
#define Pn 9
#define Dn 512
#define TBn 2048
#define G3 1536
#define NCH 16
#define DD2 262144

using short8 = __attribute__((ext_vector_type(8))) short;
using f32x4  = __attribute__((ext_vector_type(4))) float;
typedef unsigned long long ull;
typedef unsigned int uint;

__device__ __forceinline__ float fsigmoid(float x){ return 1.0f/(1.0f+__expf(-x)); }
__device__ __forceinline__ ushort f2bf(float x){
  unsigned u = __float_as_uint(x);
  return (ushort)((u + 0x7FFFu + ((u>>16)&1u)) >> 16);
}
__device__ __forceinline__ float bf2f(ushort h){
  return __uint_as_float(((unsigned)h)<<16);
}
__device__ __forceinline__ uint pk32(float x){
  ushort h = f2bf(x);
  ushort l = f2bf(x - bf2f(h));
  return ((uint)h << 16) | (uint)l;
}

// device-coherent (agent) relaxed accessors: bypass non-coherent L1/L2.
__device__ __forceinline__ ull ld_agent8(const ull* p){
  return __hip_atomic_load(p, __ATOMIC_RELAXED, __HIP_MEMORY_SCOPE_AGENT);
}
__device__ __forceinline__ void st_agent8(ull* p, ull v){
  __hip_atomic_store(p, v, __ATOMIC_RELAXED, __HIP_MEMORY_SCOPE_AGENT);
}
__device__ __forceinline__ unsigned ld_agent4(const int* p){
  return (unsigned)__hip_atomic_load(p, __ATOMIC_RELAXED, __HIP_MEMORY_SCOPE_AGENT);
}
__device__ __forceinline__ void st_agent4(int* p, int v){
  __hip_atomic_store(p, v, __ATOMIC_RELAXED, __HIP_MEMORY_SCOPE_AGENT);
}
__device__ __forceinline__ float ulo(ull v){ return __uint_as_float((unsigned)v); }
__device__ __forceinline__ float uhi(ull v){ return __uint_as_float((unsigned)(v>>32)); }
__device__ __forceinline__ ull upack(float a, float b){
  return ((ull)__float_as_uint(b) << 32) | (ull)__float_as_uint(a);
}
__device__ __forceinline__ float wave_red(float a){
  a += __shfl_xor(a, 1);  a += __shfl_xor(a, 2);  a += __shfl_xor(a, 4);
  a += __shfl_xor(a, 8);  a += __shfl_xor(a, 16); a += __shfl_xor(a, 32);
  return a;
}

// ---------- prep ----------
__global__ void k_prep(const float* __restrict__ qmask, int* __restrict__ qi,
                       int* __restrict__ qni, float* __restrict__ h0A,
                       float* __restrict__ h0B, float* __restrict__ out,
                       int* __restrict__ counts, int* __restrict__ lists,
                       int* __restrict__ dcnt, int* __restrict__ dlist,
                       int* __restrict__ rowflag){
  int t = blockIdx.x; int tid = threadIdx.x;
  int gidx = blockIdx.x*256 + tid;
  if (gidx < 16) counts[gidx] = 0;
  if (gidx < Bn*Pn*NCH) st_agent4(&rowflag[gidx], 0);
  for (int i=gidx; i<9*4096; i+=64*256) lists[i] = -1;
  __shared__ int qis[32], qnis[32];
  __shared__ int cnt9[9];
  if (tid < 9) cnt9[tid] = 0;
  if (tid < Bn){
    int b = tid;
    const float* qm = qmask + ((size_t)t*Bn + b)*Pn;
    int best = 0; float bv = qm[0];
    #pragma unroll
    for (int p=1;p<Pn;p++){ float v=qm[p]; if (v>bv){bv=v;best=p;} }
    qi[t*Bn+b] = best; qis[b] = best;
    int tn = (t==Tn-1)? t : t+1;
    const float* qmn = qmask + ((size_t)tn*Bn + b)*Pn;
    best = 0; bv = qmn[0];
    #pragma unroll
    for (int p=1;p<Pn;p++){ float v=qmn[p]; if (v>bv){bv=v;best=p;} }
    qni[t*Bn+b] = best; qnis[b] = best;
  }
  __syncthreads();
  if (tid < Bn){
    int sp = qis[tid], lp = qnis[tid];
    if (sp == lp){
      int i = atomicAdd(&cnt9[sp], 1);
      dlist[(t*9+sp)*32 + i] = tid | 256 | 512;
    } else {
      int i = atomicAdd(&cnt9[sp], 1);
      dlist[(t*9+sp)*32 + i] = tid | 256;
      int j = atomicAdd(&cnt9[lp], 1);
      dlist[(t*9+lp)*32 + j] = tid | 512;
    }
  }
  __syncthreads();
  if (tid < 9) dcnt[t*9+tid] = cnt9[tid];
  for (int i=tid; i<2304; i+=256){ h0A[t*2304 + i] = 0.f; h0B[t*2304 + i] = 0.f; }
  for (int i=tid; i<256;  i+=256) out[t*256 + i] = 0.f;
}

// ---------- aux: gather lists, ver-pack, WpT transpose-pack, cvec & C dots ----------
__global__ __launch_bounds__(256) void k_aux(
    const int* __restrict__ qi, const int* __restrict__ qni,
    int* __restrict__ counts, int* __restrict__ lists,
    const int* __restrict__ dcnt, int* __restrict__ dlist,
    const float* __restrict__ Wq, const float* __restrict__ Wih,
    const float* __restrict__ Wp, const float* __restrict__ bp,
    const float* __restrict__ bq, const float* __restrict__ bih,
    ushort* __restrict__ WpTpk, float* __restrict__ cvec,
    float* __restrict__ C1, float* __restrict__ C3){
  int bx = blockIdx.x, tid = threadIdx.x;
  if (bx < 16){
    int id = bx*256 + tid;
    int role = id >> 11, tb = id & (TBn-1);
    int p = role ? qni[tb] : qi[tb];
    int slot = atomicAdd(&counts[p], 1);
    lists[p*4096 + slot] = id;
  } else if (bx == 16){
    for (int idx = tid; idx < Bn*Pn; idx += 256){
      int b = idx / Pn, pp = idx % Pn;
      int v = 0;
      for (int t=0;t<Tn;t++){
        if (qi[t*Bn+b]==pp || qni[t*Bn+b]==pp){
          int nn = dcnt[t*9+pp];
          int base = (t*9+pp)*32;
          for (int i=0;i<nn;i++){
            if ((dlist[base+i] & 31) == b){ dlist[base+i] |= (v<<16); break; }
          }
          v++;
        }
      }
    }
  } else if (bx < 33){
    // transpose-pack Wp0^T (rows 0..511) and Wp2^T (rows 512..1023)
    int g = (bx-17)*256 + tid;          // 0..4095
    int r = g >> 3, cb = (g & 7)*64;
    #pragma unroll
    for (int mi=0; mi<2; mi++){
      const float* src = Wp + (size_t)mi*2*DD2;
      ushort* dst = WpTpk + (size_t)(mi*512 + r)*1024;
      for (int c=cb; c<cb+64; c++){
        float v = src[(size_t)c*512 + r];
        ushort h = f2bf(v);
        dst[c] = h; dst[512+c] = f2bf(v - bf2f(h));
      }
    }
  } else {
    int wv = (bx-33)*4 + (tid>>6), lane = tid & 63;
    if (wv < 16){
      // cvec1 (rows 0..511) / cvec3 (rows 512..1023)
      for (int i=0;i<64;i++){
        int r = wv*64 + i;
        int m = r >> 9, j = r & 511;
        const float* wrow = Wq + (size_t)(m?3:1)*DD2 + (size_t)j*512;
        const float* bpv  = bp + (m? 1024 : 0);
        float acc = 0.f;
        #pragma unroll
        for (int e=0;e<8;e++) acc = fmaf(wrow[lane*8+e], bpv[lane*8+e], acc);
        acc = wave_red(acc);
        if (lane==0) cvec[r] = acc + bq[(m?1536:512) + j];
      }
    } else if (wv < 232){
      int base = (wv-16)*64;
      for (int i=0;i<64;i++){
        int r = base + i;               // 0..13823  (p*1536 + j)
        const float* wrow = Wih + (size_t)r*512;
        float a1=0.f, a3=0.f;
        #pragma unroll
        for (int e=0;e<8;e++){
          float wv8 = wrow[lane*8+e];
          a1 = fmaf(wv8, bp[512 + lane*8+e], a1);
          a3 = fmaf(wv8, bp[1536 + lane*8+e], a3);
        }
        a1 = wave_red(a1); a3 = wave_red(a3);
        if (lane==0){ C1[r] = a1 + bih[r]; C3[r] = a3 + bih[r]; }
      }
    }
  }
}

// ---------- batched f32 -> [hi|lo] bf16 pack ----------
struct PkD { const float* s; ushort* d; int n; };
__global__ __launch_bounds__(256) void k_packB(PkD p0, PkD p1, PkD p2, PkD p3,
                                               PkD p4, PkD p5, PkD p6, PkD p7){
  PkD D;
  switch (blockIdx.z){
    case 0: D=p0; break; case 1: D=p1; break; case 2: D=p2; break; case 3: D=p3; break;
    case 4: D=p4; break; case 5: D=p5; break; case 6: D=p6; break; default: D=p7; break;
  }
  int total = D.n * 128;
  for (int idx = blockIdx.x*256 + threadIdx.x; idx < total; idx += gridDim.x*256){
    int r = idx >> 7, c4 = idx & 127;
    float4 v = ((const float4*)D.s)[idx];
    ushort h0=f2bf(v.x), h1=f2bf(v.y), h2=f2bf(v.z), h3=f2bf(v.w);
    ushort l0=f2bf(v.x-bf2f(h0)), l1=f2bf(v.y-bf2f(h1)),
           l2=f2bf(v.z-bf2f(h2)), l3=f2bf(v.w-bf2f(h3));
    ushort* base = D.d + (size_t)r*1024;
    *(ushort4*)(base + c4*4)       = make_ushort4(h0,h1,h2,h3);
    *(ushort4*)(base + 512 + c4*4) = make_ushort4(l0,l1,l2,l3);
  }
}

// ---------- batched MFMA GEMM, 64x64 tile, single-pass K (hi/lo co-staged) ----------
struct MMd {
  const ushort* A; const ushort* B; float* C; const float* bias; ushort* Cpk;
  int asr, ahi, alo, bsr, bhi, blo, ldc, gx;
};
__global__ __launch_bounds__(256) void k_mmB(MMd d0, MMd d1, MMd d2, MMd d3){
  MMd d;
  switch (blockIdx.z){
    case 0: d=d0; break; case 1: d=d1; break; case 2: d=d2; break; default: d=d3; break;
  }
  if ((int)blockIdx.x >= d.gx) return;
  __shared__ ushort AshH[64*64];
  __shared__ ushort AshL[64*64];
  __shared__ ushort BshH[64*64];
  __shared__ ushort BshL[64*64];
  int bm = blockIdx.y*64, bn = blockIdx.x*64;
  int tid = threadIdx.x;
  int lane = tid & 63, w = tid >> 6;
  int wm = (w>>1)*32, wn = (w&1)*32;
  f32x4 acc[2][2] = {};
  int r0 = tid >> 3, g0 = tid & 7;
  int r1 = r0 + 32;
  const ushort* Ah = d.A + d.ahi;
  const ushort* Al = d.A + d.alo;
  const ushort* Bh = d.B + d.bhi;
  const ushort* Bl = d.B + d.blo;
  for (int k0=0; k0<512; k0+=64){
    short8 vah0 = *(const short8*)(Ah + (size_t)(bm+r0)*d.asr + k0 + g0*8);
    short8 vah1 = *(const short8*)(Ah + (size_t)(bm+r1)*d.asr + k0 + g0*8);
    short8 val0 = *(const short8*)(Al + (size_t)(bm+r0)*d.asr + k0 + g0*8);
    short8 val1 = *(const short8*)(Al + (size_t)(bm+r1)*d.asr + k0 + g0*8);
    short8 vbh0 = *(const short8*)(Bh + (size_t)(bn+r0)*d.bsr + k0 + g0*8);
    short8 vbh1 = *(const short8*)(Bh + (size_t)(bn+r1)*d.bsr + k0 + g0*8);
    short8 vbl0 = *(const short8*)(Bl + (size_t)(bn+r0)*d.bsr + k0 + g0*8);
    short8 vbl1 = *(const short8*)(Bl + (size_t)(bn+r1)*d.bsr + k0 + g0*8);
    __syncthreads();
    *(short8*)(AshH + r0*64 + ((g0 ^ (r0&7))*8)) = vah0;
    *(short8*)(AshH + r1*64 + ((g0 ^ (r1&7))*8)) = vah1;
    *(short8*)(AshL + r0*64 + ((g0 ^ (r0&7))*8)) = val0;
    *(short8*)(AshL + r1*64 + ((g0 ^ (r1&7))*8)) = val1;
    *(short8*)(BshH + r0*64 + ((g0 ^ (r0&7))*8)) = vbh0;
    *(short8*)(BshH + r1*64 + ((g0 ^ (r1&7))*8)) = vbh1;
    *(short8*)(BshL + r0*64 + ((g0 ^ (r0&7))*8)) = vbl0;
    *(short8*)(BshL + r1*64 + ((g0 ^ (r1&7))*8)) = vbl1;
    __syncthreads();
    #pragma unroll
    for (int kk=0; kk<2; ++kk){
      int gs = kk*4 + (lane>>4);
      short8 afh[2], afl[2], bfh[2], bfl[2];
      #pragma unroll
      for (int mi=0; mi<2; ++mi){
        int row = wm + mi*16 + (lane&15);
        afh[mi] = *(const short8*)(AshH + row*64 + ((gs ^ (row&7))*8));
        afl[mi] = *(const short8*)(AshL + row*64 + ((gs ^ (row&7))*8));
      }
      #pragma unroll
      for (int ni=0; ni<2; ++ni){
        int row = wn + ni*16 + (lane&15);
        bfh[ni] = *(const short8*)(BshH + row*64 + ((gs ^ (row&7))*8));
        bfl[ni] = *(const short8*)(BshL + row*64 + ((gs ^ (row&7))*8));
      }
      #pragma unroll
      for (int mi=0; mi<2; ++mi)
        #pragma unroll
        for (int ni=0; ni<2; ++ni){
          acc[mi][ni] = __builtin_amdgcn_mfma_f32_16x16x32_bf16(afh[mi], bfh[ni], acc[mi][ni], 0,0,0);
          acc[mi][ni] = __builtin_amdgcn_mfma_f32_16x16x32_bf16(afh[mi], bfl[ni], acc[mi][ni], 0,0,0);
          acc[mi][ni] = __builtin_amdgcn_mfma_f32_16x16x32_bf16(afl[mi], bfh[ni], acc[mi][ni], 0,0,0);
        }
    }
  }
  #pragma unroll
  for (int mi=0; mi<2; ++mi){
    #pragma unroll
    for (int ni=0; ni<2; ++ni){
      #pragma unroll
      for (int i=0;i<4;i++){
        int row = bm + wm + mi*16 + (lane>>4)*4 + i;
        int col = bn + wn + ni*16 + (lane&15);
        float v = acc[mi][ni][i];
        if (d.bias) v += d.bias[col];
        if (d.C) d.C[(size_t)row*d.ldc + col] = v;
        if (d.Cpk){
          ushort h = f2bf(v);
          d.Cpk[(size_t)row*2*d.ldc + col] = h;
          d.Cpk[(size_t)row*2*d.ldc + d.ldc + col] = f2bf(v - bf2f(h));
        }
      }
    }
  }
}

// ---------- gather MFMA GEMM, 64x64 tile, single-pass K: G = pkx @ Wih_p^T (raw) ----------
__global__ __launch_bounds__(256) void k_mm_g(
    const ushort* __restrict__ Spk0, const ushort* __restrict__ Spk1,
    const ushort* __restrict__ Wihpk,
    const int* __restrict__ counts, const int* __restrict__ lists,
    float* __restrict__ gis, float* __restrict__ gil)
{
  int p = blockIdx.z;
  int mt = blockIdx.y;
  if (mt*64 >= counts[p]) return;
  int bn = blockIdx.x*64;
  __shared__ ushort AshH[64*64];
  __shared__ ushort AshL[64*64];
  __shared__ ushort BshH[64*64];
  __shared__ ushort BshL[64*64];
  __shared__ int rid[64];
  int tid = threadIdx.x;
  int lane = tid & 63, w = tid >> 6;
  int wm = (w>>1)*32, wn = (w&1)*32;
  if (tid < 64) rid[tid] = lists[p*4096 + mt*64 + tid];
  __syncthreads();
  f32x4 acc[2][2] = {};
  int r0 = tid >> 3, g0 = tid & 7;
  int r1 = r0 + 32;
  int id0 = rid[r0], id1 = rid[r1];
  const ushort* As0 = (id0 >= 0) ? (((id0>>11)? Spk1:Spk0) + (size_t)(id0 & (TBn-1))*1024) : nullptr;
  const ushort* As1 = (id1 >= 0) ? (((id1>>11)? Spk1:Spk0) + (size_t)(id1 & (TBn-1))*1024) : nullptr;
  const ushort* Wb  = Wihpk + (size_t)(p*G3 + bn)*1024;
  short8 zz = {0,0,0,0,0,0,0,0};
  for (int k0=0; k0<512; k0+=64){
    short8 vah0 = As0 ? *(const short8*)(As0 + k0 + g0*8)       : zz;
    short8 val0 = As0 ? *(const short8*)(As0 + 512 + k0 + g0*8) : zz;
    short8 vah1 = As1 ? *(const short8*)(As1 + k0 + g0*8)       : zz;
    short8 val1 = As1 ? *(const short8*)(As1 + 512 + k0 + g0*8) : zz;
    short8 vbh0 = *(const short8*)(Wb + (size_t)r0*1024 + k0 + g0*8);
    short8 vbl0 = *(const short8*)(Wb + (size_t)r0*1024 + 512 + k0 + g0*8);
    short8 vbh1 = *(const short8*)(Wb + (size_t)r1*1024 + k0 + g0*8);
    short8 vbl1 = *(const short8*)(Wb + (size_t)r1*1024 + 512 + k0 + g0*8);
    __syncthreads();
    *(short8*)(AshH + r0*64 + ((g0 ^ (r0&7))*8)) = vah0;
    *(short8*)(AshH + r1*64 + ((g0 ^ (r1&7))*8)) = vah1;
    *(short8*)(AshL + r0*64 + ((g0 ^ (r0&7))*8)) = val0;
    *(short8*)(AshL + r1*64 + ((g0 ^ (r1&7))*8)) = val1;
    *(short8*)(BshH + r0*64 + ((g0 ^ (r0&7))*8)) = vbh0;
    *(short8*)(BshH + r1*64 + ((g0 ^ (r1&7))*8)) = vbh1;
    *(short8*)(BshL + r0*64 + ((g0 ^ (r0&7))*8)) = vbl0;
    *(short8*)(BshL + r1*64 + ((g0 ^ (r1&7))*8)) = vbl1;
    __syncthreads();
    #pragma unroll
    for (int kk=0; kk<2; ++kk){
      int gs = kk*4 + (lane>>4);
      short8 afh[2], afl[2], bfh[2], bfl[2];
      #pragma unroll
      for (int mi=0; mi<2; ++mi){
        int row = wm + mi*16 + (lane&15);
        afh[mi] = *(const short8*)(AshH + row*64 + ((gs ^ (row&7))*8));
        afl[mi] = *(const short8*)(AshL + row*64 + ((gs ^ (row&7))*8));
      }
      #pragma unroll
      for (int ni=0; ni<2; ++ni){
        int row = wn + ni*16 + (lane&15);
        bfh[ni] = *(const short8*)(BshH + row*64 + ((gs ^ (row&7))*8));
        bfl[ni] = *(const short8*)(BshL + row*64 + ((gs ^ (row&7))*8));
      }
      #pragma unroll
      for (int mi=0; mi<2; ++mi)
        #pragma unroll
        for (int ni=0; ni<2; ++ni){
          acc[mi][ni] = __builtin_amdgcn_mfma_f32_16x16x32_bf16(afh[mi], bfh[ni], acc[mi][ni], 0,0,0);
          acc[mi][ni] = __builtin_amdgcn_mfma_f32_16x16x32_bf16(afh[mi], bfl[ni], acc[mi][ni], 0,0,0);
          acc[mi][ni] = __builtin_amdgcn_mfma_f32_16x16x32_bf16(afl[mi], bfh[ni], acc[mi][ni], 0,0,0);
        }
    }
  }
  #pragma unroll
  for (int mi=0; mi<2; ++mi){
    #pragma unroll
    for (int ni=0; ni<2; ++ni){
      #pragma unroll
      for (int i=0;i<4;i++){
        int lrow2 = wm + mi*16 + (lane>>4)*4 + i;
        int id = rid[lrow2];
        if (id < 0) continue;
        int col = bn + wn + ni*16 + (lane&15);
        float* dst = ((id>>11) ? gil : gis) + (size_t)(id & (TBn-1))*G3;
        dst[col] = acc[mi][ni][i];
      }
    }
  }
}

// ---------- tiny score kernel: both softmax stages per (t, side) ----------
__global__ __launch_bounds__(256) void k_scoreT(
    const float* __restrict__ qx0, const ushort* __restrict__ kxA,
    const float* __restrict__ qq1,
    const float* __restrict__ qx2, const ushort* __restrict__ kxB,
    const float* __restrict__ qq3,
    const float* __restrict__ cvec, float* __restrict__ scS,
    float* __restrict__ scL){
  int t = blockIdx.x, side = blockIdx.y, tid = threadIdx.x;
  const float* qx; const ushort* kx; const float* qq; const float* cv; float* sco;
  if (side==0){ qx=qx0; kx=kxA; qq=qq1; cv=cvec;     sco=scS; }
  else        { qx=qx2; kx=kxB; qq=qq3; cv=cvec+512; sco=scL; }
  __shared__ float p0[256], pA[256], pB[256];
  __shared__ float d0s[32], dAs[32], dBs[32], es[32], e1[32];
  int b = tid>>3, j = tid&7;
  const float* q   = qx + (size_t)(t*Bn+b)*Dn;
  const float* qqr = qq + (size_t)(t*Bn+b)*Dn;
  const ushort* kr = kx + (size_t)(t*Bn+b)*2048;
  float s0=0.f, sA=0.f, sB=0.f;
  for (int d=j; d<Dn; d+=8){
    float k0v = bf2f(kr[d])     + bf2f(kr[1024+d]);
    float k1v = bf2f(kr[512+d]) + bf2f(kr[1536+d]);
    s0 = fmaf(q[d],   k0v, s0);
    sA = fmaf(qqr[d], k1v, sA);
    sB = fmaf(cv[d],  k1v, sB);
  }
  p0[tid]=s0; pA[tid]=sA; pB[tid]=sB;
  __syncthreads();
  if (tid < 32){
    float a0=0,aA=0,aB=0;
    #pragma unroll
    for (int jj=0;jj<8;jj++){ a0+=p0[tid*8+jj]; aA+=pA[tid*8+jj]; aB+=pB[tid*8+jj]; }
    d0s[tid]=a0; dAs[tid]=aA; dBs[tid]=aB;
  }
  __syncthreads();
  if (tid < 32){
    float mx=d0s[0]; for(int o=1;o<32;o++) mx=fmaxf(mx,d0s[o]);
    es[tid]=__expf(d0s[tid]-mx);
  }
  __syncthreads();
  if (tid < 32){
    float sum=0; for(int o=0;o<32;o++) sum+=es[o];
    float sc0 = es[tid]/sum;
    e1[tid] = fmaf(sc0, dAs[tid], dBs[tid]);
  }
  __syncthreads();
  if (tid < 32){
    float mx=e1[0]; for(int o=1;o<32;o++) mx=fmaxf(mx,e1[o]);
    es[tid]=__expf(e1[tid]-mx);
  }
  __syncthreads();
  if (tid < 32){
    float sum=0; for(int o=0;o<32;o++) sum+=es[o];
    sco[t*Bn+tid] = es[tid]/sum;
  }
}

// ---------- persistent recurrence: rowflags + MFMA matvec + fused gi = sc*G + C ----------
#define DC 32
#define NT 6
__global__ __launch_bounds__(512, 1) void k_rec(
    float* hA, float* hB,
    const int* __restrict__ dcnt, const int* __restrict__ dlist,
    const float* __restrict__ Whh, const float* __restrict__ bhh,
    const float* __restrict__ gis, const float* __restrict__ gil,
    const float* __restrict__ scS, const float* __restrict__ scL,
    const float* __restrict__ C1, const float* __restrict__ C3,
    float* __restrict__ out, int* rowflag){
  int p  = blockIdx.x;
  int ci = blockIdx.y;
  int d0 = ci * DC;
  int tid = threadIdx.x;
  int wave = tid >> 6, lane = tid & 63;

  __shared__ float4 hsh4[16][130];
  __shared__ uint   ab16[16][516];
  __shared__ float  ghs[16][97];
  __shared__ int    dls[32];
  __shared__ float  scSsh[TBn], scLsh[TBn];

  for (int i=tid; i<TBn; i+=512){ scSsh[i]=scS[i]; scLsh[i]=scL[i]; }

  short8 Bh[16], Bl[16];
  if (wave < NT){
    int wrow = wave*16 + (lane & 15);
    int grow = (wrow >> 5)*Dn + d0 + (wrow & 31);
    const float* wsrc = Whh + ((size_t)p*G3 + grow)*Dn + (lane>>4)*8;
    #pragma unroll
    for (int ks=0; ks<16; ++ks){
      float4 w0 = *(const float4*)(wsrc + ks*32);
      float4 w1 = *(const float4*)(wsrc + ks*32 + 4);
      float xs[8] = {w0.x,w0.y,w0.z,w0.w,w1.x,w1.y,w1.z,w1.w};
      #pragma unroll
      for (int j=0;j<8;j++){
        ushort hh = f2bf(xs[j]);
        Bh[ks][j] = (short)hh;
        Bl[ks][j] = (short)f2bf(xs[j] - bf2f(hh));
      }
    }
  }
  int dd0 = (tid & 15)*2, dfix = d0 + dd0;
  float bhr0 = bhh[p*G3 + dfix],        bhr1 = bhh[p*G3 + dfix + 1];
  float bhz0 = bhh[p*G3 + Dn + dfix],   bhz1 = bhh[p*G3 + Dn + dfix + 1];
  float bhn0 = bhh[p*G3 + 2*Dn + dfix], bhn1 = bhh[p*G3 + 2*Dn + dfix + 1];
  float c1v[6], c3v[6];
  {
    const float* C1p = C1 + p*G3; const float* C3p = C3 + p*G3;
    c1v[0]=C1p[dfix];        c1v[1]=C1p[dfix+1];
    c1v[2]=C1p[Dn+dfix];     c1v[3]=C1p[Dn+dfix+1];
    c1v[4]=C1p[2*Dn+dfix];   c1v[5]=C1p[2*Dn+dfix+1];
    c3v[0]=C3p[dfix];        c3v[1]=C3p[dfix+1];
    c3v[2]=C3p[Dn+dfix];     c3v[3]=C3p[Dn+dfix+1];
    c3v[4]=C3p[2*Dn+dfix];   c3v[5]=C3p[2*Dn+dfix+1];
  }

  int entC = 0;
  if (tid < 32) entC = dlist[(0*9 + p)*32 + tid];

  for (int t=0; t<Tn; ++t){
    __syncthreads();
    if (tid < 32) dls[tid] = entC;
    __syncthreads();
    if (t+1 < Tn && tid < 32) entC = dlist[((t+1)*9 + p)*32 + tid];
    int n = dcnt[t*9+p];
    if (!n) continue;

    // G prefetch (group 0)
    float pg[12];
    {
      int i = tid >> 4;
      if (i < n && i < 16){
        int ent = dls[i]; int b = ent & 31;
        if (ent & 256){
          const float* gS = gis + (size_t)(t*Bn + b)*G3;
          pg[0]=gS[dfix]; pg[1]=gS[dfix+1]; pg[2]=gS[Dn+dfix]; pg[3]=gS[Dn+dfix+1];
          pg[4]=gS[2*Dn+dfix]; pg[5]=gS[2*Dn+dfix+1];
        }
        if (ent & 512){
          const float* gL = gil + (size_t)(t*Bn + b)*G3;
          pg[6]=gL[dfix]; pg[7]=gL[dfix+1]; pg[8]=gL[Dn+dfix]; pg[9]=gL[Dn+dfix+1];
          pg[10]=gL[2*Dn+dfix]; pg[11]=gL[2*Dn+dfix+1];
        }
      }
    }

    {
      int i0 = wave*4 + (lane >> 4);
      if (i0 < n){
        int ent = dls[i0];
        unsigned need = (unsigned)(ent >> 16);
        if (need){
          int b = ent & 31;
          const int* cell = &rowflag[(b*Pn + p)*NCH + (lane & 15)];
          while (ld_agent4(cell) < need) __builtin_amdgcn_s_sleep(1);
        }
      }
    }
    __syncthreads();

    for (int g0=0; g0<n; g0+=16){
      int gn = n - g0; if (gn > 16) gn = 16;
      for (int idx=tid; idx<gn*128; idx+=512){
        int r = idx >> 7, q = idx & 127;
        int ent = dls[g0+r];
        int b = ent & 31;
        const float* hsrc = ((ent>>16) & 1) ? hB : hA;
        const ull* src = (const ull*)(hsrc + ((size_t)b*Pn + p)*Dn) + q*2;
        ull v0 = ld_agent8(src), v1 = ld_agent8(src+1);
        float4 f; f.x = ulo(v0); f.y = uhi(v0); f.z = ulo(v1); f.w = uhi(v1);
        hsh4[r][q ^ ((q>>3)&7)] = f;
        uint4 pk; pk.x = pk32(f.x); pk.y = pk32(f.y); pk.z = pk32(f.z); pk.w = pk32(f.w);
        *(uint4*)&ab16[r][q*4] = pk;
      }
      __syncthreads();

      if (wave < NT){
        f32x4 acc = {0.f,0.f,0.f,0.f};
        int arow = lane & 15;
        int kq   = (lane >> 4)*8;
        #pragma unroll
        for (int ks=0; ks<16; ++ks){
          uint4 u0 = *(const uint4*)&ab16[arow][ks*32 + kq];
          uint4 u1 = *(const uint4*)&ab16[arow][ks*32 + kq + 4];
          uint uu[8] = {u0.x,u0.y,u0.z,u0.w,u1.x,u1.y,u1.z,u1.w};
          short8 Ah, Al;
          #pragma unroll
          for (int j=0;j<8;j++){
            Ah[j] = (short)(uu[j] >> 16);
            Al[j] = (short)(uu[j] & 0xffffu);
          }
          acc = __builtin_amdgcn_mfma_f32_16x16x32_bf16(Ah, Bh[ks], acc, 0,0,0);
          acc = __builtin_amdgcn_mfma_f32_16x16x32_bf16(Ah, Bl[ks], acc, 0,0,0);
          acc = __builtin_amdgcn_mfma_f32_16x16x32_bf16(Al, Bh[ks], acc, 0,0,0);
        }
        #pragma unroll
        for (int i=0;i<4;i++)
          ghs[(lane>>4)*4 + i][wave*16 + (lane & 15)] = acc[i];
      }
      __syncthreads();

      if (tid < gn*16){
        int i = tid >> 4;
        int ent = dls[g0+i];
        int b = ent & 31;
        bool S = (ent & 256) != 0, L = (ent & 512) != 0;
        int v = ent >> 16;
        float* hdst = (v & 1) ? hA : hB;
        int qq = dfix >> 2;
        float4 u = hsh4[i][qq ^ ((qq>>3)&7)];
        float hv0 = (dfix & 2) ? u.z : u.x;
        float hv1 = (dfix & 2) ? u.w : u.y;
        float ghr0 = ghs[i][dd0]    + bhr0, ghr1 = ghs[i][dd0+1]    + bhr1;
        float ghz0 = ghs[i][32+dd0] + bhz0, ghz1 = ghs[i][32+dd0+1] + bhz1;
        float ghn0 = ghs[i][64+dd0] + bhn0, ghn1 = ghs[i][64+dd0+1] + bhn1;
        float v0 = hv0, v1 = hv1;
        if (S){
          float g0v,g1v,g2v,g3v,g4v,g5v;
          if (g0 == 0){ g0v=pg[0]; g1v=pg[1]; g2v=pg[2]; g3v=pg[3]; g4v=pg[4]; g5v=pg[5]; }
          else {
            const float* gS = gis + (size_t)(t*Bn + b)*G3;
            g0v=gS[dfix]; g1v=gS[dfix+1]; g2v=gS[Dn+dfix]; g3v=gS[Dn+dfix+1];
            g4v=gS[2*Dn+dfix]; g5v=gS[2*Dn+dfix+1];
          }
          float sc = scSsh[t*Bn + b];
          float i0 = fmaf(sc, g0v, c1v[0]), i1 = fmaf(sc, g1v, c1v[1]);
          float i2 = fmaf(sc, g2v, c1v[2]), i3 = fmaf(sc, g3v, c1v[3]);
          float i4 = fmaf(sc, g4v, c1v[4]), i5 = fmaf(sc, g5v, c1v[5]);
          float rg0 = fsigmoid(i0 + ghr0), rg1 = fsigmoid(i1 + ghr1);
          float zg0 = fsigmoid(i2 + ghz0), zg1 = fsigmoid(i3 + ghz1);
          float ng0 = tanhf(fmaf(rg0, ghn0, i4));
          float ng1 = tanhf(fmaf(rg1, ghn1, i5));
          v0 = fmaf(zg0, hv0 - ng0, ng0);
          v1 = fmaf(zg1, hv1 - ng1, ng1);
        }
        if (L){
          float g0v,g1v,g2v,g3v,g4v,g5v;
          if (g0 == 0){ g0v=pg[6]; g1v=pg[7]; g2v=pg[8]; g3v=pg[9]; g4v=pg[10]; g5v=pg[11]; }
          else {
            const float* gL = gil + (size_t)(t*Bn + b)*G3;
            g0v=gL[dfix]; g1v=gL[dfix+1]; g2v=gL[Dn+dfix]; g3v=gL[Dn+dfix+1];
            g4v=gL[2*Dn+dfix]; g5v=gL[2*Dn+dfix+1];
          }
          float sc = scLsh[t*Bn + b];
          float i0 = fmaf(sc, g0v, c3v[0]), i1 = fmaf(sc, g1v, c3v[1]);
          float i2 = fmaf(sc, g2v, c3v[2]), i3 = fmaf(sc, g3v, c3v[3]);
          float i4 = fmaf(sc, g4v, c3v[4]), i5 = fmaf(sc, g5v, c3v[5]);
          float rg0 = fsigmoid(i0 + ghr0), rg1 = fsigmoid(i1 + ghr1);
          float zg0 = fsigmoid(i2 + ghz0), zg1 = fsigmoid(i3 + ghz1);
          float ng0 = tanhf(fmaf(rg0, ghn0, i4));
          float ng1 = tanhf(fmaf(rg1, ghn1, i5));
          float hl0 = fmaf(zg0, hv0 - ng0, ng0);
          float hl1 = fmaf(zg1, hv1 - ng1, ng1);
          if (S){ v0 += hl0 - hv0; v1 += hl1 - hv1; }
          else  { v0 = hl0; v1 = hl1; }
        }
        st_agent8((ull*)(hdst + ((size_t)b*Pn + p)*Dn + dfix), upack(v0, v1));
        if (S) *(ull*)(out + ((size_t)(t+1)*Bn + b)*Dn + dfix) = upack(v0, v1);
      }
      __syncthreads();
    }

    if (tid < n){
      int ent = dls[tid];
      st_agent4(&rowflag[((ent & 31)*Pn + p)*NCH + ci], (ent >> 16) + 1);
    }
  }
}

extern "C" void kernel_launch(void* const* d_in, const int* in_sizes, int n_in,
                              void* d_out, int out_size, void* d_ws, size_t ws_size,
                              hipStream_t stream){
  const float* U    = (const float*)d_in[0];
  const float* SK   = (const float*)d_in[1];
  const float* NU   = (const float*)d_in[2];
  const float* LK   = (const float*)d_in[3];
  const float* qmask= (const float*)d_in[5];
  const float* bk   = (const float*)d_in[7];
  const float* bq   = (const float*)d_in[9];
  const float* bp   = (const float*)d_in[11];
  const float* Wk   = (const float*)d_in[6];
  const float* Wq   = (const float*)d_in[8];
  const float* Wp   = (const float*)d_in[10];
  const float* Wih  = (const float*)d_in[12];
  const float* Whh  = (const float*)d_in[13];
  const float* bih  = (const float*)d_in[14];
  const float* bhh  = (const float*)d_in[15];
  float* out = (float*)d_out;

  char* w = (char*)d_ws;
  size_t off = 0;
  auto alloc = [&](size_t bytes)->void*{ void* p = w + off; off += (bytes + 255) & ~(size_t)255; return p; };
  ushort* SKpk  = (ushort*)alloc(2048UL*1024*2);
  ushort* LKpk  = (ushort*)alloc(2048UL*1024*2);
  ushort* Upk   = (ushort*)alloc(2048UL*1024*2);
  ushort* NUpk  = (ushort*)alloc(2048UL*1024*2);
  ushort* Wkpk  = (ushort*)alloc(2048UL*1024*2);
  ushort* Wqpk  = (ushort*)alloc(2048UL*1024*2);
  ushort* Wppk  = (ushort*)alloc(2048UL*1024*2);
  ushort* Wihpk = (ushort*)alloc(13824UL*1024*2);
  ushort* WpTpk = (ushort*)alloc(1024UL*1024*2);
  ushort* WWpk  = (ushort*)alloc(1024UL*1024*2);
  ushort* kxApk = (ushort*)alloc(2048UL*2048*2);
  ushort* kxBpk = (ushort*)alloc(2048UL*2048*2);
  ushort* pkx1pk= (ushort*)alloc(2048UL*1024*2);
  ushort* pkx3pk= (ushort*)alloc(2048UL*1024*2);
  float* qxA    = (float*)alloc(2048UL*512*4);
  float* qxB    = (float*)alloc(2048UL*512*4);
  float* qq1    = (float*)alloc(2048UL*512*4);
  float* qq3    = (float*)alloc(2048UL*512*4);
  float* gis    = (float*)alloc(2048UL*1536*4);
  float* gil    = (float*)alloc(2048UL*1536*4);
  float* hA     = (float*)alloc(32UL*9*512*4);
  float* hB     = (float*)alloc(32UL*9*512*4);
  float* cvec   = (float*)alloc(1024*4);
  float* C1     = (float*)alloc(9UL*1536*4);
  float* C3     = (float*)alloc(9UL*1536*4);
  float* scS    = (float*)alloc(2048*4);
  float* scL    = (float*)alloc(2048*4);
  int* qi       = (int*)alloc(2048*4);
  int* qni      = (int*)alloc(2048*4);
  int* counts   = (int*)alloc(16*4);
  int* lists    = (int*)alloc(9*4096*4);
  int* dcnt     = (int*)alloc(64*9*4);
  int* dlist    = (int*)alloc(64*9*32*4);
  int* rowflag  = (int*)alloc(32*9*NCH*4);
  (void)ws_size; (void)in_sizes; (void)n_in; (void)out_size;

  dim3 blk(256);

  k_prep<<<64, blk, 0, stream>>>(qmask, qi, qni, hA, hB, out, counts, lists, dcnt, dlist, rowflag);
  k_aux <<<91, blk, 0, stream>>>(qi, qni, counts, lists, dcnt, dlist,
                                 Wq, Wih, Wp, bp, bq, bih, WpTpk, cvec, C1, C3);

  {
    PkD p0{SK, SKpk, 2048}, p1{LK, LKpk, 2048}, p2{U, Upk, 2048}, p3{NU, NUpk, 2048};
    PkD p4{Wk, Wkpk, 2048}, p5{Wq, Wqpk, 2048}, p6{Wp, Wppk, 2048}, p7{Wih, Wihpk, 13824};
    k_packB<<<dim3(256,1,8), blk, 0, stream>>>(p0,p1,p2,p3,p4,p5,p6,p7);
  }

  // mm0: WW1 = Wq1 @ Wp0 ; WW3 = Wq3 @ Wp2  (packed outputs)
  {
    MMd d0{Wqpk+(size_t)512*1024,  WpTpk,                 nullptr, nullptr, WWpk,
           1024,0,512, 1024,0,512, 512, 8};
    MMd d1{Wqpk+(size_t)1536*1024, WpTpk+(size_t)512*1024, nullptr, nullptr, WWpk+(size_t)512*1024,
           1024,0,512, 1024,0,512, 512, 8};
    k_mmB<<<dim3(8,8,2), blk, 0, stream>>>(d0,d1,d0,d0);
  }

  // mm1: kx (packed) and qx0/qx2 (f32 + bias)
  {
    MMd d0{SKpk, Wkpk,                   nullptr, bk,      kxApk, 1024,0,512, 1024,0,512, 1024, 16};
    MMd d1{LKpk, Wkpk+(size_t)1024*1024, nullptr, bk+1024, kxBpk, 1024,0,512, 1024,0,512, 1024, 16};
    MMd d2{Upk,  Wqpk,                   qxA,     bq,      nullptr,1024,0,512, 1024,0,512, 512,  8};
    MMd d3{NUpk, Wqpk+(size_t)1024*1024, qxB,     bq+1024, nullptr,1024,0,512, 1024,0,512, 512,  8};
    k_mmB<<<dim3(16,32,4), blk, 0, stream>>>(d0,d1,d2,d3);
  }

  // mm2: pkx1pk = kx1@Wp1^T ; pkx3pk = kx3@Wp3^T ; qq1 = kx0@WW1^T ; qq3 = kx2@WW3^T
  {
    MMd d0{kxApk, Wppk+(size_t)512*1024,  nullptr, nullptr, pkx1pk, 2048,512,1536, 1024,0,512, 512, 8};
    MMd d1{kxBpk, Wppk+(size_t)1536*1024, nullptr, nullptr, pkx3pk, 2048,512,1536, 1024,0,512, 512, 8};
    MMd d2{kxApk, WWpk,                   qq1,     nullptr, nullptr,2048,0,  1024, 1024,0,512, 512, 8};
    MMd d3{kxBpk, WWpk+(size_t)512*1024,  qq3,     nullptr, nullptr,2048,0,  1024, 1024,0,512, 512, 8};
    k_mmB<<<dim3(8,32,4), blk, 0, stream>>>(d0,d1,d2,d3);
  }

  k_mm_g<<<dim3(24,64,9), blk, 0, stream>>>(pkx1pk, pkx3pk, Wihpk, counts, lists, gis, gil);

  k_scoreT<<<dim3(64,2), blk, 0, stream>>>(qxA, kxApk, qq1, qxB, kxBpk, qq3, cvec, scS, scL);

  k_rec<<<dim3(9,NCH), dim3(512), 0, stream>>>(hA, hB, dcnt, dlist, Whh, bhh,
                                               gis, gil, scS, scL, C1, C3, out, rowflag);
}